// Round 1
// baseline (416.041 us; speedup 1.0000x reference)
//
#include <hip/hip_runtime.h>

// g[b,h,w] = (1/N) * sum_n conj(H[n]) * (H[n]*x[b] - y[b,n])
//          = x[b]*(1/N)*sum_n |H[n]|^2  -  (1/N)*sum_n conj(H[n])*y[b,n]
//
// Round 6: occupancy fix. Old grid was P/256 = 512 blocks = 2 blocks/CU =
// 2 waves/SIMD (and ~140 VGPR capped it there too) -> delivered ~5.0 TB/s
// while the harness's own fill dispatches prove 6.6 TB/s on this chip.
// New: 4-way n-split per block (wave c handles n in [16c,16c+16) for a
// 64-wide f4 p-tile), LDS cross-wave reduce, grid = P/64 = 2048 blocks,
// groups-of-2 pipeline (12 staged f4) + __launch_bounds__(256,4) to land
// <=128 VGPR -> 4 waves/SIMD. Same exact traffic, 2x the wave parallelism.

typedef float f4 __attribute__((ext_vector_type(4)));

#define ACCUM(hv, v0, v1)                                   \
    do {                                                    \
        s0 += (hv).x * (hv).x + (hv).y * (hv).y;            \
        s1 += (hv).z * (hv).z + (hv).w * (hv).w;            \
        a00r += (hv).x * (v0).x + (hv).y * (v0).y;          \
        a00i += (hv).x * (v0).y - (hv).y * (v0).x;          \
        a01r += (hv).z * (v0).z + (hv).w * (v0).w;          \
        a01i += (hv).z * (v0).w - (hv).w * (v0).z;          \
        a10r += (hv).x * (v1).x + (hv).y * (v1).y;          \
        a10i += (hv).x * (v1).y - (hv).y * (v1).x;          \
        a11r += (hv).z * (v1).z + (hv).w * (v1).w;          \
        a11i += (hv).z * (v1).w - (hv).w * (v1).z;          \
    } while (0)

__global__ void __launch_bounds__(256, 4) idt_fused_kernel(
    const f4* __restrict__ H4,   // [N][P]
    const f4* __restrict__ Y4,   // [B=2][N][P]
    const f4* __restrict__ X4,   // [B=2][P]
    f4* __restrict__ O4,         // [B=2][P]
    const int* __restrict__ nbf,
    int N, int P)
{
    const int lane  = threadIdx.x & 63;   // p within the block's 64-wide tile
    const int chunk = threadIdx.x >> 6;   // n-chunk 0..3 (one wave each)
    const int p     = (blockIdx.x << 6) + lane;
    const int pc    = p < P ? p : P - 1;  // clamp (P is divisible; safety only)

    const int nPer  = N >> 2;             // 16 n's per wave
    const int nBase = chunk * nPer;

    float s0 = 0.f, s1 = 0.f;
    float a00r = 0.f, a00i = 0.f, a01r = 0.f, a01i = 0.f;  // b=0
    float a10r = 0.f, a10i = 0.f, a11r = 0.f, a11i = 0.f;  // b=1

    const f4* hp = H4 + (size_t)nBase * P + pc;
    const f4* y0 = Y4 + (size_t)nBase * P + pc;                 // b=0
    const f4* y1 = Y4 + ((size_t)N + nBase) * P + pc;           // b=1

    const int G = nPer >> 1;              // groups of 2 n's => 8

    f4 cH[2], c0[2], c1[2];
    #pragma unroll
    for (int j = 0; j < 2; ++j) {
        cH[j] = __builtin_nontemporal_load(hp + (size_t)j * P);
        c0[j] = __builtin_nontemporal_load(y0 + (size_t)j * P);
        c1[j] = __builtin_nontemporal_load(y1 + (size_t)j * P);
    }

    for (int g = 0; g < G - 1; ++g) {
        const size_t base = (size_t)(g + 1) * 2 * P;

        // issue next group's loads first (stay outstanding through compute)
        f4 nH[2], n0[2], n1[2];
        #pragma unroll
        for (int j = 0; j < 2; ++j) {
            nH[j] = __builtin_nontemporal_load(hp + base + (size_t)j * P);
            n0[j] = __builtin_nontemporal_load(y0 + base + (size_t)j * P);
            n1[j] = __builtin_nontemporal_load(y1 + base + (size_t)j * P);
        }

        #pragma unroll
        for (int j = 0; j < 2; ++j) ACCUM(cH[j], c0[j], c1[j]);

        #pragma unroll
        for (int j = 0; j < 2; ++j) { cH[j] = nH[j]; c0[j] = n0[j]; c1[j] = n1[j]; }
    }

    #pragma unroll
    for (int j = 0; j < 2; ++j) ACCUM(cH[j], c0[j], c1[j]);

    // ---- cross-wave reduction over the 4 n-chunks --------------------------
    // [10][4][64] floats: for fixed (k,chunk) lanes hit consecutive dwords ->
    // 2 lanes/bank (free); same for the read side. 10.25 KB LDS/block.
    __shared__ float red[10][4][64];
    red[0][chunk][lane] = s0;   red[1][chunk][lane] = s1;
    red[2][chunk][lane] = a00r; red[3][chunk][lane] = a00i;
    red[4][chunk][lane] = a01r; red[5][chunk][lane] = a01i;
    red[6][chunk][lane] = a10r; red[7][chunk][lane] = a10i;
    red[8][chunk][lane] = a11r; red[9][chunk][lane] = a11i;
    __syncthreads();

    if (chunk == 0 && p < P) {
        #pragma unroll
        for (int c = 1; c < 4; ++c) {
            s0   += red[0][c][lane]; s1   += red[1][c][lane];
            a00r += red[2][c][lane]; a00i += red[3][c][lane];
            a01r += red[4][c][lane]; a01i += red[5][c][lane];
            a10r += red[6][c][lane]; a10i += red[7][c][lane];
            a11r += red[8][c][lane]; a11i += red[9][c][lane];
        }

        const float inv = 1.0f / (float)nbf[0];

        f4 x0 = X4[p];
        f4 x1 = X4[(size_t)P + p];

        f4 o0, o1;
        o0.x = (x0.x * s0 - a00r) * inv;
        o0.y = (x0.y * s0 - a00i) * inv;
        o0.z = (x0.z * s1 - a01r) * inv;
        o0.w = (x0.w * s1 - a01i) * inv;

        o1.x = (x1.x * s0 - a10r) * inv;
        o1.y = (x1.y * s0 - a10i) * inv;
        o1.z = (x1.z * s1 - a11r) * inv;
        o1.w = (x1.w * s1 - a11i) * inv;

        __builtin_nontemporal_store(o0, O4 + p);
        __builtin_nontemporal_store(o1, O4 + (size_t)P + p);
    }
}

extern "C" void kernel_launch(void* const* d_in, const int* in_sizes, int n_in,
                              void* d_out, int out_size, void* d_ws, size_t ws_size,
                              hipStream_t stream) {
    const float* f_ipt = (const float*)d_in[0];   // [B,H,W,2]
    const float* f_y   = (const float*)d_in[1];   // [B,N,H,W,2]
    const float* Hreal = (const float*)d_in[2];   // [N,H,W,2]
    const int*   nbf   = (const int*)d_in[3];     // scalar NBFkeep

    const int B = in_sizes[1] / in_sizes[2];      // = 2
    const int N = in_sizes[1] / in_sizes[0];      // = 64
    const int P = in_sizes[0] / B / 4;            // = 131072 float4 groups per batch

    dim3 block(256);
    dim3 grid((P + 63) / 64);                     // 64 f4-columns per block
    idt_fused_kernel<<<grid, block, 0, stream>>>(
        (const f4*)Hreal, (const f4*)f_y, (const f4*)f_ipt,
        (f4*)d_out, nbf, N, P);
}